// Round 16
// baseline (357.960 us; speedup 1.0000x reference)
//
#include <hip/hip_runtime.h>
#include <hip/hip_bf16.h>

#define MDIM 4096
#define DDIM 2048
#define HDIM 2048
#define EDIM 8
#define HD   ((size_t)HDIM * DDIM)

typedef float v4f __attribute__((ext_vector_type(4)));
typedef int   v4i __attribute__((ext_vector_type(4)));
typedef int   v8i __attribute__((ext_vector_type(8)));

// async global->LDS, 16B per lane. lds pointer must be wave-uniform
// (HW writes base + lane*16).
__device__ __forceinline__ void gl2lds16(const void* g, void* l) {
  __builtin_amdgcn_global_load_lds(
      (const __attribute__((address_space(1))) void*)g,
      (__attribute__((address_space(3))) void*)l,
      16, 0, 0);
}

// ---------------- Kernel 1: gating softmax + fp8 quantize of x ----------------
__global__ __launch_bounds__(256) void k_gate_xq(
    const float* __restrict__ x, const float* __restrict__ gw,
    const float* __restrict__ gb, float* __restrict__ gate,
    unsigned char* __restrict__ x8)
{
  const int wid  = threadIdx.x >> 6;
  const int lane = threadIdx.x & 63;
  const int m    = blockIdx.x * 4 + wid;

  const float4* xr = (const float4*)(x + (size_t)m * DDIM);
  unsigned int* qr = (unsigned int*)(x8 + (size_t)m * DDIM);

  float part[EDIM];
#pragma unroll
  for (int e = 0; e < EDIM; ++e) part[e] = 0.f;

#pragma unroll
  for (int it = 0; it < DDIM / 4 / 64; ++it) {   // 8 iterations
    const int idx = it * 64 + lane;
    const float4 xv = xr[idx];
    int pk = __builtin_amdgcn_cvt_pk_fp8_f32(xv.x, xv.y, 0, false);
    pk = __builtin_amdgcn_cvt_pk_fp8_f32(xv.z, xv.w, pk, true);
    qr[idx] = (unsigned int)pk;
#pragma unroll
    for (int e = 0; e < EDIM; ++e) {
      const float4 wv = ((const float4*)(gw + (size_t)e * DDIM))[idx];
      part[e] += xv.x * wv.x + xv.y * wv.y + xv.z * wv.z + xv.w * wv.w;
    }
  }
#pragma unroll
  for (int e = 0; e < EDIM; ++e) {
#pragma unroll
    for (int off = 32; off > 0; off >>= 1)
      part[e] += __shfl_xor(part[e], off);
  }
  float lg[EDIM];
  float s = 0.f;
#pragma unroll
  for (int e = 0; e < EDIM; ++e) lg[e] = part[e] + gb[e];
  float mx = lg[0];
#pragma unroll
  for (int e = 1; e < EDIM; ++e) mx = fmaxf(mx, lg[e]);
#pragma unroll
  for (int e = 0; e < EDIM; ++e) { lg[e] = expf(lg[e] - mx); s += lg[e]; }
  const float inv = 1.f / s;
  if (lane < EDIM) gate[m * EDIM + lane] = lg[lane] * inv;
}

// ---------------- Kernel 2: fp8 quantize of expert_w --------------------------
__global__ void k_wq(const float* __restrict__ w, unsigned char* __restrict__ w8)
{
  const long long n4 = (long long)EDIM * HDIM * DDIM / 4;
  const long long stride = (long long)gridDim.x * blockDim.x;
  for (long long i = (long long)blockIdx.x * blockDim.x + threadIdx.x; i < n4;
       i += stride) {
    const float4 v = ((const float4*)w)[i];
    int pk = __builtin_amdgcn_cvt_pk_fp8_f32(v.x, v.y, 0, false);
    pk = __builtin_amdgcn_cvt_pk_fp8_f32(v.z, v.w, pk, true);
    ((unsigned int*)w8)[i] = (unsigned int)pk;
  }
}

// ---------------- Kernel 3: fused grouped GEMM + gated combine ----------------
// R15 skeleton + ONE-STEP REGISTER PREFETCH OF B (R15's miss: B loads issued
// in-step exposed ~300-600cy L2/L3 latency per step -> MfmaUtil 18.7%).
//  - dynamic s-loop unrolled x2 for bvA/bvB ping-pong (no reg copies);
//    body(s) issues B(s+1) loads right after the barrier -> latency hides
//    under body(s)'s 16 MFMAs.
//  - Ordering without sched fences: STAGE_A(s+1) issued FIRST, then an empty
//    asm memory fence pins A-group OLDER than B-group in the VMEM queue, so
//    top-of-step vmcnt(8) (= the 8 B(s) loads legitimately in flight) waits
//    exactly for A(s)'s gl2lds before s_barrier + ds_read.
//  - acc C-chained (AGPR), gate folded at expert boundary (R11 numerics).
//  - Arch budget ~120 (bvA 32 + bvB 32 + av 32 transient + addr) + 128 AGPR;
//    under the 128-arch half at 2 waves/SIMD (R15 measured 96 with less).
// 256 thr (4 waves 2m x 2n, 64x64/wave), tile 128x128, 512 blocks = 2
// independent blocks/CU. LDS: 2x16K A dbuf + 4K gates.
__global__ __launch_bounds__(256, 2) void k_moe_gemm(
    const unsigned char* __restrict__ x8,   // [M, D]
    const unsigned char* __restrict__ w8,   // [E, H, D]
    const float* __restrict__ gate,         // [M, 8]
    float* __restrict__ out)                // [M, H] f32
{
  extern __shared__ unsigned char smem[];   // 2*16K A + 4K gates = 36864 B

  const int tid  = threadIdx.x;
  const int lane = tid & 63;
  const int wid  = tid >> 6;        // 0..3
  const int wm   = wid >> 1;        // 0..1  (64-row group)
  const int wn   = wid & 1;         // 0..1  (64-col group)

  // XCD chunking: 512 blocks; each XCD owns an 8x8 square of (m,h) tiles.
  const int bid   = blockIdx.x;
  const int xcd   = bid & 7;
  const int local = bid >> 3;                        // 0..63
  const int tm    = (xcd >> 1) * 8 + (local >> 3);   // 0..31
  const int tn    = (xcd & 1) * 8 + (local & 7);     // 0..15
  const int bm    = tm * 128;
  const int bn    = tn * 128;

  const int lrow = lane & 15;
  const int lk   = lane >> 4;                  // 0..3 -> 32B k-block
  const int c0   = (lk * 32) ^ ((lrow & 7) << 4);   // swizzled A read cols
  const int c1   = c0 ^ 16;

  // A staging coords (inverse-swizzled source; LDS dest linear)
  const int strow = tid >> 3;                  // 0..31
  const int stcol = ((tid & 7) * 16) ^ ((strow & 7) << 4);
  const unsigned char* asrc = x8 + (size_t)(bm + strow) * DDIM + stcol;

  // B fragment base pointer (per lane, direct global)
  const unsigned char* bptr =
      w8 + (size_t)(bn + wn * 64 + lrow) * DDIM + lk * 32;

  float* sGf = (float*)(smem + 32768);         // [8 experts][128 rows]

  // gate cache: threads 0..127 own row bm+tid for all 8 experts
  if (tid < 128) {
    const float4 g0 = *(const float4*)(gate + (size_t)(bm + tid) * EDIM);
    const float4 g1 = *(const float4*)(gate + (size_t)(bm + tid) * EDIM + 4);
    sGf[0 * 128 + tid] = g0.x; sGf[1 * 128 + tid] = g0.y;
    sGf[2 * 128 + tid] = g0.z; sGf[3 * 128 + tid] = g0.w;
    sGf[4 * 128 + tid] = g1.x; sGf[5 * 128 + tid] = g1.y;
    sGf[6 * 128 + tid] = g1.z; sGf[7 * 128 + tid] = g1.w;
  }

  v4f acc[4][4];      // per-expert partial, mfma C-chained (AGPR)
  v4f outacc[4][4];   // gated running sum (AGPR-foldable)
#pragma unroll
  for (int i = 0; i < 4; ++i)
#pragma unroll
    for (int j = 0; j < 4; ++j) {
      acc[i][j][0] = 0.f; acc[i][j][1] = 0.f;
      acc[i][j][2] = 0.f; acc[i][j][3] = 0.f;
      outacc[i][j][0] = 0.f; outacc[i][j][1] = 0.f;
      outacc[i][j][2] = 0.f; outacc[i][j][3] = 0.f;
    }

  v8i bvA[4], bvB[4];   // B fragment double buffer (loop-carried)

// stage A k-tile of step S into abuf[S&1]: 4 gl2lds16/thread
#define STAGE_A(S) do {                                                        \
    const int kb_ = ((S) & 15) * 128;                                          \
    unsigned char* la_ = smem + ((S) & 1) * 16384;                             \
    _Pragma("unroll") for (int i = 0; i < 4; ++i)                              \
      gl2lds16(asrc + (size_t)i * (32 * DDIM) + kb_,                           \
               (void*)(la_ + i * 4096 + wid * 1024));                          \
  } while (0)

// load B fragments of step S into BV (8x dwordx4, direct global)
#define LOAD_B(S, BV) do {                                                     \
    const unsigned char* pbe_ = bptr + (size_t)((S) >> 4) * HD +               \
                                (size_t)(((S) & 15) * 128);                    \
    _Pragma("unroll") for (int j = 0; j < 4; ++j) {                            \
      const unsigned char* pb_ = pbe_ + (size_t)j * (16 * DDIM);               \
      union { v8i v; v4i h[2]; } u_;                                           \
      u_.h[0] = *(const v4i*)(pb_);                                            \
      u_.h[1] = *(const v4i*)(pb_ + 16);                                       \
      BV[j] = u_.v;                                                            \
    }                                                                          \
  } while (0)

// one step: consume BVC (loaded last step), prefetch BVN for next step
#define BODY(S, BVC, BVN) do {                                                 \
    asm volatile("s_waitcnt vmcnt(8)" ::: "memory");  /* A(S) done */          \
    __builtin_amdgcn_s_barrier();                                              \
    if ((S) < 127) {                                                           \
      STAGE_A((S) + 1);                                                        \
      asm volatile("" ::: "memory");   /* pin A-group older than B-group */    \
      LOAD_B((S) + 1, BVN);                                                    \
    }                                                                          \
    v8i av[4];                                                                 \
    {                                                                          \
      const unsigned char* pA_ = smem + ((S) & 1) * 16384 +                    \
                                 (size_t)(wm * 64 + lrow) * 128;               \
      _Pragma("unroll") for (int f = 0; f < 4; ++f) {                          \
        union { v8i v; v4i h[2]; } u_;                                         \
        u_.h[0] = *(const v4i*)(pA_ + f * 2048 + c0);                          \
        u_.h[1] = *(const v4i*)(pA_ + f * 2048 + c1);                          \
        av[f] = u_.v;                                                          \
      }                                                                        \
    }                                                                          \
    __builtin_amdgcn_s_setprio(1);                                             \
    _Pragma("unroll") for (int j = 0; j < 4; ++j)                              \
      _Pragma("unroll") for (int i = 0; i < 4; ++i)                            \
        acc[i][j] = __builtin_amdgcn_mfma_scale_f32_16x16x128_f8f6f4(          \
            av[i], BVC[j], acc[i][j], 0 /*fp8*/, 0 /*fp8*/,                    \
            0, 127 /*e8m0 1.0*/, 0, 127 /*e8m0 1.0*/);                         \
    __builtin_amdgcn_s_setprio(0);                                             \
    if (((S) & 15) == 15) {     /* expert boundary: fold gate, reset acc */    \
      const int e_ = (S) >> 4;                                                 \
      _Pragma("unroll") for (int i = 0; i < 4; ++i) {                          \
        const v4f g4_ =                                                        \
            *(const v4f*)(sGf + e_ * 128 + wm * 64 + i * 16 + lk * 4);         \
        _Pragma("unroll") for (int j = 0; j < 4; ++j) {                        \
          outacc[i][j][0] += g4_[0] * acc[i][j][0]; acc[i][j][0] = 0.f;        \
          outacc[i][j][1] += g4_[1] * acc[i][j][1]; acc[i][j][1] = 0.f;        \
          outacc[i][j][2] += g4_[2] * acc[i][j][2]; acc[i][j][2] = 0.f;        \
          outacc[i][j][3] += g4_[3] * acc[i][j][3]; acc[i][j][3] = 0.f;        \
        }                                                                      \
      }                                                                        \
    }                                                                          \
  } while (0)

  // prologue: stage A(0), load B(0), publish gates; drain everything once
  STAGE_A(0);
  LOAD_B(0, bvA);
  __syncthreads();

  for (int s = 0; s < 128; s += 2) {
    BODY(s,     bvA, bvB);
    BODY(s + 1, bvB, bvA);
  }

#undef BODY
#undef LOAD_B
#undef STAGE_A

  // epilogue: direct coalesced stores (single block per output tile)
#pragma unroll
  for (int i = 0; i < 4; ++i)
#pragma unroll
    for (int q = 0; q < 4; ++q) {
      const size_t r = (size_t)(bm + wm * 64 + i * 16 + lk * 4 + q);
      float* orow = out + r * HDIM + bn + wn * 64 + lrow;
#pragma unroll
      for (int j = 0; j < 4; ++j)
        orow[j * 16] = outacc[i][j][q];
    }
}

extern "C" void kernel_launch(void* const* d_in, const int* in_sizes, int n_in,
                              void* d_out, int out_size, void* d_ws, size_t ws_size,
                              hipStream_t stream) {
  (void)in_sizes; (void)n_in; (void)out_size; (void)ws_size;
  const float* x        = (const float*)d_in[0];
  const float* gate_w   = (const float*)d_in[1];
  const float* gate_b   = (const float*)d_in[2];
  const float* expert_w = (const float*)d_in[3];
  float* out = (float*)d_out;

  char* ws = (char*)d_ws;
  float* gate       = (float*)ws;                                   // 131072 B
  unsigned char* x8 = (unsigned char*)(ws + 131072);                // 8 MiB
  unsigned char* w8 = (unsigned char*)(ws + 131072 + (size_t)MDIM * DDIM);

  hipLaunchKernelGGL(k_gate_xq, dim3(MDIM / 4), dim3(256), 0, stream,
                     x, gate_w, gate_b, gate, x8);
  hipLaunchKernelGGL(k_wq, dim3(4096), dim3(256), 0, stream, expert_w, w8);
  hipLaunchKernelGGL(k_moe_gemm, dim3(512), dim3(256), 36864, stream,
                     x8, w8, gate, out);
}

// Round 17
// 158.930 us; speedup vs baseline: 2.2523x; 2.2523x over previous
//
#include <hip/hip_runtime.h>
#include <hip/hip_bf16.h>

#define MDIM 4096
#define DDIM 2048
#define HDIM 2048
#define EDIM 8
#define HD   ((size_t)HDIM * DDIM)

typedef float v4f __attribute__((ext_vector_type(4)));
typedef int   v4i __attribute__((ext_vector_type(4)));
typedef int   v8i __attribute__((ext_vector_type(8)));

// async global->LDS, 16B per lane. lds pointer must be wave-uniform
// (HW writes base + lane*16).
__device__ __forceinline__ void gl2lds16(const void* g, void* l) {
  __builtin_amdgcn_global_load_lds(
      (const __attribute__((address_space(1))) void*)g,
      (__attribute__((address_space(3))) void*)l,
      16, 0, 0);
}

// ------------- Kernel 1: fused {gating softmax + x fp8} | {w fp8} ------------
// blocks 0..1023: gate+xq (1 wave per row). blocks 1024..5119: w quantize.
// Both HBM-streaming and independent -> fusing overlaps their memory phases.
__global__ __launch_bounds__(256) void k_quant(
    const float* __restrict__ x, const float* __restrict__ gw,
    const float* __restrict__ gb, const float* __restrict__ w,
    float* __restrict__ gate, unsigned char* __restrict__ x8,
    unsigned char* __restrict__ w8)
{
  if (blockIdx.x < 1024) {
    const int wid  = threadIdx.x >> 6;
    const int lane = threadIdx.x & 63;
    const int m    = blockIdx.x * 4 + wid;

    const float4* xr = (const float4*)(x + (size_t)m * DDIM);
    unsigned int* qr = (unsigned int*)(x8 + (size_t)m * DDIM);

    float part[EDIM];
#pragma unroll
    for (int e = 0; e < EDIM; ++e) part[e] = 0.f;

#pragma unroll
    for (int it = 0; it < DDIM / 4 / 64; ++it) {   // 8 iterations
      const int idx = it * 64 + lane;
      const float4 xv = xr[idx];
      int pk = __builtin_amdgcn_cvt_pk_fp8_f32(xv.x, xv.y, 0, false);
      pk = __builtin_amdgcn_cvt_pk_fp8_f32(xv.z, xv.w, pk, true);
      qr[idx] = (unsigned int)pk;
#pragma unroll
      for (int e = 0; e < EDIM; ++e) {
        const float4 wv = ((const float4*)(gw + (size_t)e * DDIM))[idx];
        part[e] += xv.x * wv.x + xv.y * wv.y + xv.z * wv.z + xv.w * wv.w;
      }
    }
#pragma unroll
    for (int e = 0; e < EDIM; ++e) {
#pragma unroll
      for (int off = 32; off > 0; off >>= 1)
        part[e] += __shfl_xor(part[e], off);
    }
    float lg[EDIM];
    float s = 0.f;
#pragma unroll
    for (int e = 0; e < EDIM; ++e) lg[e] = part[e] + gb[e];
    float mx = lg[0];
#pragma unroll
    for (int e = 1; e < EDIM; ++e) mx = fmaxf(mx, lg[e]);
#pragma unroll
    for (int e = 0; e < EDIM; ++e) { lg[e] = expf(lg[e] - mx); s += lg[e]; }
    const float inv = 1.f / s;
    if (lane < EDIM) gate[m * EDIM + lane] = lg[lane] * inv;
  } else {
    const long long n4 = (long long)EDIM * HDIM * DDIM / 4;
    const long long stride = (long long)4096 * 256;
    for (long long i = (long long)(blockIdx.x - 1024) * 256 + threadIdx.x;
         i < n4; i += stride) {
      const float4 v = ((const float4*)w)[i];
      int pk = __builtin_amdgcn_cvt_pk_fp8_f32(v.x, v.y, 0, false);
      pk = __builtin_amdgcn_cvt_pk_fp8_f32(v.z, v.w, pk, true);
      ((unsigned int*)w8)[i] = (unsigned int)pk;
    }
  }
}

// ---------------- Kernel 2: fused grouped GEMM + gated combine ----------------
// R11 (133us, MfmaUtil 45.8%, VGPR 100, clean) with ONE surgical change:
// single barrier per step. STAGE(s+1) moves AFTER the barrier (R13/R15's
// proven-safe ordering): vmcnt(0) -> s_barrier -> STAGE(s+1) -> COMP(s).
//  - Race-free: buf[(s+1)&1] was last read in COMP(s-1); every wave passed
//    barrier(s) only after finishing COMP(s-1).
//  - vmcnt(0) waits on loads issued a full step (~2000cy) earlier -> cheap.
//  - Halves barrier count (256->128) and removes the end-of-step convoy.
// Everything else R11-identical: e-outer linear steps s=e*16+kt, A/B dbuf
// via global_load_lds + both-sides XOR swizzle, C-chained acc (AGPR),
// outacc gate-fold at expert boundaries, 256thr/4 waves 2m x 2n (64x64),
// tile 128x128, 512 blocks = 2 independent blocks/CU, setprio around MFMA.
// Register law (R5..R16, 11 points): only MFMA-C-chained state may be
// loop-carried; ds/global-produced registers crossing fences -> 128-cap spill.
__global__ __launch_bounds__(256, 2) void k_moe_gemm(
    const unsigned char* __restrict__ x8,   // [M, D]
    const unsigned char* __restrict__ w8,   // [E, H, D]
    const float* __restrict__ gate,         // [M, 8]
    float* __restrict__ out)                // [M, H] f32
{
  extern __shared__ unsigned char smem[];   // 2*16K A + 2*16K B + 4K G = 68K

  const int tid  = threadIdx.x;
  const int lane = tid & 63;
  const int wid  = tid >> 6;        // 0..3
  const int wm   = wid >> 1;        // 0..1  (64-row group)
  const int wn   = wid & 1;         // 0..1  (64-col group)

  // XCD chunking: 512 blocks; each XCD owns an 8x8 square of (m,h) tiles.
  const int bid   = blockIdx.x;
  const int xcd   = bid & 7;
  const int local = bid >> 3;                        // 0..63
  const int tm    = (xcd >> 1) * 8 + (local >> 3);   // 0..31
  const int tn    = (xcd & 1) * 8 + (local & 7);     // 0..15
  const int bm    = tm * 128;
  const int bn    = tn * 128;

  const int lrow = lane & 15;
  const int lk   = lane >> 4;                  // 0..3 -> 32B k-block
  const int c0   = (lk * 32) ^ ((lrow & 7) << 4);
  const int c1   = c0 ^ 16;

  // staging coords: thread covers row strow of each 32-row slab,
  // inverse-swizzled col stcol (involution within the 128B row).
  const int strow = tid >> 3;                  // 0..31
  const int stcol = ((tid & 7) * 16) ^ ((strow & 7) << 4);
  const unsigned char* asrc = x8 + (size_t)(bm + strow) * DDIM + stcol;
  const unsigned char* bsrc = w8 + (size_t)(bn + strow) * DDIM + stcol;

  float* sGf = (float*)(smem + 65536);         // [8 experts][128 rows]

  // gate cache: threads 0..127 own row bm+tid for all 8 experts
  if (tid < 128) {
    const float4 g0 = *(const float4*)(gate + (size_t)(bm + tid) * EDIM);
    const float4 g1 = *(const float4*)(gate + (size_t)(bm + tid) * EDIM + 4);
    sGf[0 * 128 + tid] = g0.x; sGf[1 * 128 + tid] = g0.y;
    sGf[2 * 128 + tid] = g0.z; sGf[3 * 128 + tid] = g0.w;
    sGf[4 * 128 + tid] = g1.x; sGf[5 * 128 + tid] = g1.y;
    sGf[6 * 128 + tid] = g1.z; sGf[7 * 128 + tid] = g1.w;
  }

  v4f acc[4][4];      // per-expert partial, mfma C-chained (AGPR)
  v4f outacc[4][4];   // gated running sum (AGPR-foldable)
#pragma unroll
  for (int i = 0; i < 4; ++i)
#pragma unroll
    for (int j = 0; j < 4; ++j) {
      acc[i][j][0] = 0.f; acc[i][j][1] = 0.f;
      acc[i][j][2] = 0.f; acc[i][j][3] = 0.f;
      outacc[i][j][0] = 0.f; outacc[i][j][1] = 0.f;
      outacc[i][j][2] = 0.f; outacc[i][j][3] = 0.f;
    }

// stage step S (A k-tile + B tile) into buf[S&1]: 4 + 4 loads/thread
#define STAGE(S) do {                                                          \
    const int    kb_ = ((S) & 15) * 128;                                       \
    const size_t eo_ = (size_t)((S) >> 4) * HD;                                \
    unsigned char* la_ = smem + ((S) & 1) * 16384;                             \
    unsigned char* lb_ = smem + 32768 + ((S) & 1) * 16384;                     \
    _Pragma("unroll") for (int i = 0; i < 4; ++i)                              \
      gl2lds16(asrc + (size_t)i * (32 * DDIM) + kb_,                           \
               (void*)(la_ + i * 4096 + wid * 1024));                          \
    _Pragma("unroll") for (int i = 0; i < 4; ++i)                              \
      gl2lds16(bsrc + eo_ + (size_t)i * (32 * DDIM) + kb_,                     \
               (void*)(lb_ + i * 4096 + wid * 1024));                          \
  } while (0)

#define COMP(S) do {                                                           \
    const unsigned char* pA_ = smem + ((S) & 1) * 16384 +                      \
                               (size_t)(wm * 64 + lrow) * 128;                 \
    const unsigned char* pB_ = smem + 32768 + ((S) & 1) * 16384 +              \
                               (size_t)(wn * 64 + lrow) * 128;                 \
    v8i bv_[4];                                                                \
    _Pragma("unroll") for (int j = 0; j < 4; ++j) {                            \
      union { v8i v; v4i h[2]; } u_;                                           \
      u_.h[0] = *(const v4i*)(pB_ + j * 2048 + c0);                            \
      u_.h[1] = *(const v4i*)(pB_ + j * 2048 + c1);                            \
      bv_[j] = u_.v;                                                           \
    }                                                                          \
    __builtin_amdgcn_s_setprio(1);                                             \
    _Pragma("unroll") for (int i = 0; i < 4; ++i) {                            \
      union { v8i v; v4i h[2]; } ua_;                                          \
      ua_.h[0] = *(const v4i*)(pA_ + i * 2048 + c0);                           \
      ua_.h[1] = *(const v4i*)(pA_ + i * 2048 + c1);                           \
      const v8i av_ = ua_.v;                                                   \
      _Pragma("unroll") for (int j = 0; j < 4; ++j)                            \
        acc[i][j] = __builtin_amdgcn_mfma_scale_f32_16x16x128_f8f6f4(          \
            av_, bv_[j], acc[i][j], 0 /*fp8*/, 0 /*fp8*/,                      \
            0, 127 /*e8m0 1.0*/, 0, 127 /*e8m0 1.0*/);                         \
    }                                                                          \
    __builtin_amdgcn_s_setprio(0);                                             \
    if (((S) & 15) == 15) {     /* expert boundary: fold gate, reset acc */    \
      const int e_ = (S) >> 4;                                                 \
      _Pragma("unroll") for (int i = 0; i < 4; ++i) {                          \
        const v4f g4_ =                                                        \
            *(const v4f*)(sGf + e_ * 128 + wm * 64 + i * 16 + lk * 4);         \
        _Pragma("unroll") for (int j = 0; j < 4; ++j) {                        \
          outacc[i][j][0] += g4_[0] * acc[i][j][0]; acc[i][j][0] = 0.f;        \
          outacc[i][j][1] += g4_[1] * acc[i][j][1]; acc[i][j][1] = 0.f;        \
          outacc[i][j][2] += g4_[2] * acc[i][j][2]; acc[i][j][2] = 0.f;        \
          outacc[i][j][3] += g4_[3] * acc[i][j][3]; acc[i][j][3] = 0.f;        \
        }                                                                      \
      }                                                                        \
    }                                                                          \
  } while (0)

  // prologue: stage step 0; publish gate cache; drain
  STAGE(0);
  __syncthreads();

  // main loop: ONE barrier per step; stage-after-barrier (race-free)
  for (int s = 0; s < 128; ++s) {
    asm volatile("s_waitcnt vmcnt(0)" ::: "memory");
    __builtin_amdgcn_s_barrier();
    if (s < 127) STAGE(s + 1);
    COMP(s);
  }

#undef COMP
#undef STAGE

  // epilogue: direct coalesced stores (single block per output tile)
#pragma unroll
  for (int i = 0; i < 4; ++i)
#pragma unroll
    for (int q = 0; q < 4; ++q) {
      const size_t r = (size_t)(bm + wm * 64 + i * 16 + lk * 4 + q);
      float* orow = out + r * HDIM + bn + wn * 64 + lrow;
#pragma unroll
      for (int j = 0; j < 4; ++j)
        orow[j * 16] = outacc[i][j][q];
    }
}

extern "C" void kernel_launch(void* const* d_in, const int* in_sizes, int n_in,
                              void* d_out, int out_size, void* d_ws, size_t ws_size,
                              hipStream_t stream) {
  (void)in_sizes; (void)n_in; (void)out_size; (void)ws_size;
  const float* x        = (const float*)d_in[0];
  const float* gate_w   = (const float*)d_in[1];
  const float* gate_b   = (const float*)d_in[2];
  const float* expert_w = (const float*)d_in[3];
  float* out = (float*)d_out;

  char* ws = (char*)d_ws;
  float* gate       = (float*)ws;                                   // 131072 B
  unsigned char* x8 = (unsigned char*)(ws + 131072);                // 8 MiB
  unsigned char* w8 = (unsigned char*)(ws + 131072 + (size_t)MDIM * DDIM);

  hipLaunchKernelGGL(k_quant, dim3(5120), dim3(256), 0, stream,
                     x, gate_w, gate_b, expert_w, gate, x8, w8);
  hipLaunchKernelGGL(k_moe_gemm, dim3(512), dim3(256), 69632, stream,
                     x8, w8, gate, out);
}